// Round 9
// baseline (977.578 us; speedup 1.0000x reference)
//
#include <hip/hip_runtime.h>

// SubsetGFlowNetTB: 17-step GFlowNet trajectory-balance forward.
// R9 = R8 + 4 blocks/CU (16 waves): LDS 47104 -> 40896 (<= 160K/4) via
// c-coef table -> 16 pre-loop registers, ebh -> bf16, meta int -> short+uchar,
// selw -> permuted-bit selp[16][32] (fragment-order bits: per-pass mask is one
// 16-bit bfe; t+1 patch folds into the mask word). launch_bounds(256,4):
// budget 128 >= natural ~100 unified regs (R8 measured 84), no forced spill.

#define NEG_INF (-1000000000.0f)
#define LOG2E 1.4426950408889634f
#define LN2   0.6931471805599453f

// amask bits: [9:0] action (1023 = dead), [13] full, [14] new
#define A_FULL 0x2000
#define A_NEW  0x4000

typedef short bf16x8 __attribute__((ext_vector_type(8)));
typedef float f32x16 __attribute__((ext_vector_type(16)));

__device__ __forceinline__ unsigned short f2bf(float x){
  unsigned int u = __float_as_uint(x);
  u = (u + 0x7FFFu + ((u >> 16) & 1u)) >> 16;   // RNE
  return (unsigned short)u;
}
__device__ __forceinline__ float bf2f(unsigned short h){
  return __uint_as_float(((unsigned int)h) << 16);
}
__device__ __forceinline__ unsigned int cvt_pk_bf16(float lo, float hi){
  unsigned int r;
  asm("v_cvt_pk_bf16_f32 %0, %1, %2" : "=v"(r) : "v"(lo), "v"(hi));
  return r;
}

// ---------------------------------------------------------------------------
// Prep: W2 (256x256 f32), Wh (256x513 f32) -> bf16 MFMA fragments.
// Fragment: lane l of tile (kt,ntg) holds M[kt*16+(l>>5)*8+i][ntg*32+(l&31)].
// whf is PRE-SCALED by log2(e) so phase C can use v_exp2 directly.
// ---------------------------------------------------------------------------
__global__ void prep_kernel(const float* __restrict__ W2, const float* __restrict__ Wh,
                            unsigned short* __restrict__ w2f, unsigned short* __restrict__ whf,
                            float* __restrict__ whstop){
  int id = blockIdx.x * 256 + threadIdx.x;
  if (id < 8192){                       // W2 fragments
    int lane = id & 63; int tile = id >> 6;   // tile = kt*8 + ntg
    int ntg = tile & 7, kt = tile >> 3;
    int col = ntg * 32 + (lane & 31);
    int k0  = kt * 16 + (lane >> 5) * 8;
    unsigned int u[4];
#pragma unroll
    for (int p = 0; p < 4; ++p){
      unsigned short lo = f2bf(W2[(k0 + 2*p    ) * 256 + col]);
      unsigned short hi = f2bf(W2[(k0 + 2*p + 1) * 256 + col]);
      u[p] = (unsigned int)lo | ((unsigned int)hi << 16);
    }
    *(uint4*)(w2f + (size_t)id * 8) = make_uint4(u[0], u[1], u[2], u[3]);
  } else if (id < 24576){               // Wh fragments (asset cols 0..511), x log2e
    int id2 = id - 8192;
    int lane = id2 & 63; int tile = id2 >> 6; // tile = kt*16 + ntg
    int ntg = tile & 15, kt = tile >> 4;
    int col = ntg * 32 + (lane & 31);
    int k0  = kt * 16 + (lane >> 5) * 8;
    unsigned int u[4];
#pragma unroll
    for (int p = 0; p < 4; ++p){
      unsigned short lo = f2bf(Wh[(k0 + 2*p    ) * 513 + col] * LOG2E);
      unsigned short hi = f2bf(Wh[(k0 + 2*p + 1) * 513 + col] * LOG2E);
      u[p] = (unsigned int)lo | ((unsigned int)hi << 16);
    }
    *(uint4*)(whf + (size_t)id2 * 8) = make_uint4(u[0], u[1], u[2], u[3]);
  } else if (id < 24832){               // stop column, f32, unscaled
    int k = id - 24576;
    whstop[k] = Wh[k * 513 + 512];
  }
}

// ---------------------------------------------------------------------------
// Fused kernel: 256 threads (4 waves) own 32 samples, 9 chunks x 2 steps.
// Single h tile [64 rows][256 feats] bf16 (h1 then h2 per 32-row pass);
// rows 0-31 = step t, 32-63 = t+1. Byte-XOR swizzle ((row&15)<<4).
// ---------------------------------------------------------------------------
__launch_bounds__(256, 4)
__global__ void gfn_kernel(const int* __restrict__ actions, const float* __restrict__ rp,
                           const float* __restrict__ W1, const float* __restrict__ b1,
                           const float* __restrict__ b2, const float* __restrict__ bh,
                           const unsigned short* __restrict__ w2f,
                           const unsigned short* __restrict__ whf,
                           const float* __restrict__ whstop,
                           float* __restrict__ out)
{
  __shared__ alignas(16) unsigned short h[64 * 256];    // 32768 (h1, then h2)
  __shared__ alignas(16) float b2s[256];                // 1024
  __shared__ alignas(16) unsigned short ebh16[512];     // 1024 exp(bh) bf16
  __shared__ alignas(16) unsigned int selp[16][32];     // 2048 permuted sel bits
  __shared__ alignas(16) unsigned short whst_h[256];    // 512 stop col bf16
  __shared__ short amask[18][32];                       // 1152
  __shared__ unsigned char kc[18][32];                  // 576
  __shared__ float stopl[64];                           // 256
  __shared__ float chosen[64];                          // 256
  __shared__ float pred_s[64][4];                       // 1024
  __shared__ float logpf_s[32];                         // 128
  __shared__ float rp_s[32];                            // 128  => total 40896

  const int tid  = threadIdx.x;
  const int wave = tid >> 6;            // 0..3
  const int lane = tid & 63;
  const int ln5  = lane & 31;
  const int lg2  = lane >> 5;
  const int base = blockIdx.x * 32;

  // ---- init ----
  b2s[tid] = b2[tid];
  whst_h[tid] = f2bf(whstop[tid]);
  for (int i = tid; i < 512; i += 256) ebh16[i] = f2bf(__expf(bh[i]));
  const float stopbias = bh[512];
  for (int i = tid; i < 512; i += 256) ((unsigned int*)selp)[i] = 0u;
  int* acts = (int*)h;                  // stage actions in h scratch
  for (int i = tid; i < 544; i += 256) acts[i] = actions[base * 17 + i];
  if (tid < 32){ logpf_s[tid] = 0.f; rp_s[tid] = rp[base + tid]; }
  // layer-1 coefficient rows in REGISTERS (coalesced, loop-invariant)
  const float4 ck4 = *(const float4*)(W1 + (size_t)512 * 256 + lane * 4);
  const float4 ct4 = *(const float4*)(W1 + (size_t)513 * 256 + lane * 4);
  const float4 cr4 = *(const float4*)(W1 + (size_t)514 * 256 + lane * 4);
  const float4 cb4 = *(const float4*)(b1 + lane * 4);
  __syncthreads();

  // ---- state precompute: O(17^2) scan per sample; no GEMM dependency ----
  if (tid < 32){
    int s = tid, k = 0;
    for (int t = 0; t < 17; ++t){
      int a = acts[s * 17 + t];
      bool alive = (a >= 0);
      bool isnew = alive && (a < 512);
      if (isnew){
        for (int u = 0; u < t; ++u) if (acts[s * 17 + u] == a){ isnew = false; break; }
      }
      int av = alive ? a : 1023;
      amask[t][s] = (short)(av | (isnew ? A_NEW : 0) | ((k >= 16) ? A_FULL : 0));
      kc[t][s] = (unsigned char)k;
      if (isnew) ++k;
    }
    amask[17][s] = (short)(1023 | ((k >= 16) ? A_FULL : 0));
    kc[17][s] = (unsigned char)k;
  }
  // packed layer-1 running sum: Spk[2*s8+{0,1}] = bf16x2 of feats {0,1},{2,3}
  unsigned int Spk[16];
#pragma unroll
  for (int j = 0; j < 16; ++j) Spk[j] = 0u;
  __syncthreads();

  char* hb = (char*)h;

#pragma unroll 1
  for (int c = 0; c < 9; ++c){
    const int t = c * 2;

    // ---- Phase A: h1 rows for steps t and t+1; thread=(4 feats, 8 samples) ----
    {
      float tf = (float)t;
      float c00 = cb4.x + tf * ct4.x, c01 = cb4.y + tf * ct4.y;
      float c02 = cb4.z + tf * ct4.z, c03 = cb4.w + tf * ct4.w;
      float c10 = c00 + ct4.x, c11 = c01 + ct4.y, c12 = c02 + ct4.z, c13 = c03 + ct4.w;
#pragma unroll
      for (int s8 = 0; s8 < 8; ++s8){
        int s = wave * 8 + s8;
        float rv = rp_s[s];
        int m0 = amask[t][s];
        int m1 = amask[t + 1][s];
        unsigned int pk0 = Spk[s8 * 2], pk1 = Spk[s8 * 2 + 1];
        float S0 = __uint_as_float(pk0 << 16);
        float S1 = __uint_as_float(pk0 & 0xFFFF0000u);
        float S2 = __uint_as_float(pk1 << 16);
        float S3 = __uint_as_float(pk1 & 0xFFFF0000u);
        float kf = (float)kc[t][s];
        {
          float v0 = fmaxf(S0 + kf * ck4.x + rv * cr4.x + c00, 0.f);
          float v1 = fmaxf(S1 + kf * ck4.y + rv * cr4.y + c01, 0.f);
          float v2 = fmaxf(S2 + kf * ck4.z + rv * cr4.z + c02, 0.f);
          float v3 = fmaxf(S3 + kf * ck4.w + rv * cr4.w + c03, 0.f);
          int byte = (s * 512 + lane * 8) ^ ((s & 15) << 4);
          *(uint2*)(hb + byte) = make_uint2(cvt_pk_bf16(v0, v1), cvt_pk_bf16(v2, v3));
        }
        if (m0 & A_NEW){
          int a = m0 & 1023;
          float4 w = *(const float4*)(W1 + (size_t)a * 256 + lane * 4);
          S0 += w.x; S1 += w.y; S2 += w.z; S3 += w.w;
        }
        float kf1 = (float)kc[t + 1][s];
        {
          float v0 = fmaxf(S0 + kf1 * ck4.x + rv * cr4.x + c10, 0.f);
          float v1 = fmaxf(S1 + kf1 * ck4.y + rv * cr4.y + c11, 0.f);
          float v2 = fmaxf(S2 + kf1 * ck4.z + rv * cr4.z + c12, 0.f);
          float v3 = fmaxf(S3 + kf1 * ck4.w + rv * cr4.w + c13, 0.f);
          int byte = ((32 + s) * 512 + lane * 8) ^ ((s & 15) << 4);
          *(uint2*)(hb + byte) = make_uint2(cvt_pk_bf16(v0, v1), cvt_pk_bf16(v2, v3));
        }
        if (m1 & A_NEW){
          int a = m1 & 1023;
          float4 w = *(const float4*)(W1 + (size_t)a * 256 + lane * 4);
          S0 += w.x; S1 += w.y; S2 += w.z; S3 += w.w;
        }
        if ((m0 | m1) & A_NEW){
          Spk[s8 * 2]     = cvt_pk_bf16(S0, S1);
          Spk[s8 * 2 + 1] = cvt_pk_bf16(S2, S3);
        }
      }
    }
    __syncthreads();

    // ---- Phase B (swapped): D'[feat][row]; 2 sequential passes over the
    //      SINGLE h buffer: read h1 rows [32q,+32), barrier, overwrite with h2.
#pragma unroll 1
    for (int q = 0; q < 2; ++q){
      f32x16 aB0, aB1;
#pragma unroll
      for (int i = 0; i < 16; ++i){ aB0[i] = 0.f; aB1[i] = 0.f; }
#pragma unroll 4
      for (int kt = 0; kt < 16; ++kt){
        int off = kt * 32 + lg2 * 16;
        int rr = q * 32 + ln5;
        bf16x8 sf = *(const bf16x8*)(hb + ((rr * 512 + off) ^ ((ln5 & 15) << 4)));
        bf16x8 w0 = *(const bf16x8*)(w2f + ((size_t)((kt * 8 + wave * 2    ) * 64 + lane)) * 8);
        bf16x8 w1 = *(const bf16x8*)(w2f + ((size_t)((kt * 8 + wave * 2 + 1) * 64 + lane)) * 8);
        aB0 = __builtin_amdgcn_mfma_f32_32x32x16_bf16(w0, sf, aB0, 0, 0, 0);
        aB1 = __builtin_amdgcn_mfma_f32_32x32x16_bf16(w1, sf, aB1, 0, 0, 0);
      }
      __syncthreads();   // all waves done reading h1 rows [32q,+32)
      int rr = q * 32 + ln5;
#pragma unroll
      for (int g = 0; g < 4; ++g){
        int f0 = wave * 64 + g * 8 + lg2 * 4;
        int f1 = f0 + 32;
        float4 bb0 = *(const float4*)&b2s[f0];
        float4 bb1 = *(const float4*)&b2s[f1];
        {
          float v0 = fmaxf(aB0[g*4+0] + bb0.x, 0.f), v1 = fmaxf(aB0[g*4+1] + bb0.y, 0.f);
          float v2 = fmaxf(aB0[g*4+2] + bb0.z, 0.f), v3 = fmaxf(aB0[g*4+3] + bb0.w, 0.f);
          int byte = (rr * 512 + f0 * 2) ^ ((ln5 & 15) << 4);
          *(uint2*)(hb + byte) = make_uint2(cvt_pk_bf16(v0, v1), cvt_pk_bf16(v2, v3));
        }
        {
          float v0 = fmaxf(aB1[g*4+0] + bb1.x, 0.f), v1 = fmaxf(aB1[g*4+1] + bb1.y, 0.f);
          float v2 = fmaxf(aB1[g*4+2] + bb1.z, 0.f), v3 = fmaxf(aB1[g*4+3] + bb1.w, 0.f);
          int byte = (rr * 512 + f1 * 2) ^ ((ln5 & 15) << 4);
          *(uint2*)(hb + byte) = make_uint2(cvt_pk_bf16(v0, v1), cvt_pk_bf16(v2, v3));
        }
      }
    }
    __syncthreads();   // h2 fully written

    // ---- stop logit (col 512): 4 threads/row, 64 rows ----
    {
      int row = tid >> 2, f4 = tid & 3;
      float sp = 0.f;
#pragma unroll
      for (int c8 = 0; c8 < 8; ++c8){
        int sl = c8 * 4 + f4;
        int byte = (row * 512 + sl * 16) ^ ((row & 15) << 4);
        uint4 q = *(const uint4*)(hb + byte);
        unsigned int qq[4] = {q.x, q.y, q.z, q.w};
#pragma unroll
        for (int p = 0; p < 4; ++p){
          int f = sl * 8 + 2 * p;
          sp += bf2f((unsigned short)(qq[p] & 0xFFFFu)) * bf2f(whst_h[f])
              + bf2f((unsigned short)(qq[p] >> 16))     * bf2f(whst_h[f + 1]);
        }
      }
      sp += __shfl_xor(sp, 1);
      sp += __shfl_xor(sp, 2);
      if (f4 == 0){
        int kcv = kc[t + (row >> 5)][row & 31];
        stopl[row] = (kcv == 0) ? NEG_INF : sp + stopbias;
      }
    }

    // ---- Phase C (swapped): lane owns sample ln5 (both steps); one whf fetch
    //      serves both row-tiles. 4 passes, 2 accs each.
    {
      int mt  = amask[t][ln5];
      int mt1 = amask[t + 1][ln5];
      int av0 = mt & 1023, av1 = mt1 & 1023;
      bool g0 = av0 < 512;                  // alive asset action at step t
      bool g1 = av1 < 512;
      int pa = (mt & A_NEW) ? av0 : -1;     // patch col for step t+1 mask
      float sum0 = 0.f, sum1 = 0.f;
#pragma unroll 1
      for (int p = 0; p < 4; ++p){
        int pt = wave * 4 + p;
        f32x16 a0, a1;
#pragma unroll
        for (int i = 0; i < 16; ++i){ a0[i] = 0.f; a1[i] = 0.f; }
#pragma unroll 4
        for (int kt = 0; kt < 16; ++kt){
          int off = kt * 32 + lg2 * 16;
          bf16x8 b0 = *(const bf16x8*)(hb + ((ln5 * 512 + off) ^ ((ln5 & 15) << 4)));
          bf16x8 b1_ = *(const bf16x8*)(hb + (((32 + ln5) * 512 + off) ^ ((ln5 & 15) << 4)));
          bf16x8 w = *(const bf16x8*)(whf + ((size_t)((kt * 16 + pt) * 64 + lane)) * 8);
          a0 = __builtin_amdgcn_mfma_f32_32x32x16_bf16(w, b0, a0, 0, 0, 0);
          a1 = __builtin_amdgcn_mfma_f32_32x32x16_bf16(w, b1_, a1, 0, 0, 0);
        }
        // per-pass 16-bit masks in fragment order (bit r)
        unsigned wsel = (selp[pt][ln5] >> (lg2 * 16)) & 0xFFFFu;
        unsigned m0_16 = (mt  & A_FULL) ? 0xFFFFu : wsel;
        unsigned m1_16 = (mt1 & A_FULL) ? 0xFFFFu : wsel;
        if (pa >= 0 && (pa >> 5) == pt && (((pa >> 2) & 1) == lg2))
          m1_16 |= 1u << ((pa & 3) | (((pa >> 3) & 3) << 2));
        int tr0 = (g0 && (av0 >> 5) == pt && (((av0 >> 2) & 1) == lg2))
                  ? ((av0 & 3) | (((av0 >> 3) & 3) << 2)) : -1;
        int tr1 = (g1 && (av1 >> 5) == pt && (((av1 >> 2) & 1) == lg2))
                  ? ((av1 & 3) | (((av1 >> 3) & 3) << 2)) : -1;
        float c0v = 0.f, c0e = 1.f, c1v = 0.f, c1e = 1.f;
#pragma unroll
        for (int g = 0; g < 4; ++g){
          const ushort4 ebu = *(const ushort4*)&ebh16[pt * 32 + g * 8 + lg2 * 4];
          float ee[4] = { bf2f(ebu.x), bf2f(ebu.y), bf2f(ebu.z), bf2f(ebu.w) };
#pragma unroll
          for (int j = 0; j < 4; ++j){
            int r = g * 4 + j;
            float v0 = ((m0_16 >> r) & 1u) ? NEG_INF : a0[r];
            float v1 = ((m1_16 >> r) & 1u) ? NEG_INF : a1[r];
            sum0 = fmaf(__builtin_amdgcn_exp2f(v0), ee[j], sum0);
            sum1 = fmaf(__builtin_amdgcn_exp2f(v1), ee[j], sum1);
            if (r == tr0){ c0v = v0; c0e = ee[j]; }
            if (r == tr1){ c1v = v1; c1e = ee[j]; }
          }
        }
        if (tr0 >= 0) chosen[ln5]      = (c0v == NEG_INF) ? NEG_INF : fmaf(c0v, LN2, __logf(c0e));
        if (tr1 >= 0) chosen[32 + ln5] = (c1v == NEG_INF) ? NEG_INF : fmaf(c1v, LN2, __logf(c1e));
      }
      sum0 += __shfl_xor(sum0, 32);
      sum1 += __shfl_xor(sum1, 32);
      if (lg2 == 0){ pred_s[ln5][wave] = sum0; pred_s[32 + ln5][wave] = sum1; }
    }
    __syncthreads();

    // ---- finalize both steps: lse, logpf, selp commit ----
    if (tid < 32){
      int s = tid;
      int m0 = amask[t][s];
      int m1 = amask[t + 1][s];
      int av0 = m0 & 1023, av1 = m1 & 1023;
      {
        float tot = __expf(stopl[s]) + pred_s[s][0] + pred_s[s][1] + pred_s[s][2] + pred_s[s][3];
        float lse = __logf(tot);
        if (av0 != 1023) logpf_s[s] += ((av0 == 512) ? stopl[s] : chosen[s]) - lse;
        if (m0 & A_NEW){
          int pt = av0 >> 5, rf = av0 & 31;
          selp[pt][s] |= 1u << ((((rf >> 2) & 1) << 4) | (rf & 3) | (((rf >> 3) & 3) << 2));
        }
      }
      {
        int row = 32 + s;
        float tot = __expf(stopl[row]) + pred_s[row][0] + pred_s[row][1] + pred_s[row][2] + pred_s[row][3];
        float lse = __logf(tot);
        if (av1 != 1023) logpf_s[s] += ((av1 == 512) ? stopl[row] : chosen[row]) - lse;
        if (m1 & A_NEW){
          int pt = av1 >> 5, rf = av1 & 31;
          selp[pt][s] |= 1u << ((((rf >> 2) & 1) << 4) | (rf & 3) | (((rf >> 3) & 3) << 2));
        }
      }
    }
    __syncthreads();
  } // chunk loop

  if (tid < 32) out[base + tid] = logpf_s[tid];
}

extern "C" void kernel_launch(void* const* d_in, const int* in_sizes, int n_in,
                              void* d_out, int out_size, void* d_ws, size_t ws_size,
                              hipStream_t stream)
{
  const int*   actions = (const int*)d_in[0];
  const float* rp  = (const float*)d_in[1];
  const float* W1  = (const float*)d_in[2];
  const float* b1  = (const float*)d_in[3];
  const float* W2  = (const float*)d_in[4];
  const float* b2  = (const float*)d_in[5];
  const float* Wh  = (const float*)d_in[6];
  const float* bh  = (const float*)d_in[7];
  float* out = (float*)d_out;

  unsigned short* w2f = (unsigned short*)d_ws;          // 65536  bf16 (128 KB)
  unsigned short* whf = w2f + 65536;                    // 131072 bf16 (256 KB)
  float* whstop = (float*)(whf + 131072);               // 256 f32

  prep_kernel<<<97, 256, 0, stream>>>(W2, Wh, w2f, whf, whstop);
  gfn_kernel<<<2048, 256, 0, stream>>>(actions, rp, W1, b1, b2, bh, w2f, whf, whstop, out);
}

// Round 10
// 762.779 us; speedup vs baseline: 1.2816x; 1.2816x over previous
//
#include <hip/hip_runtime.h>

// SubsetGFlowNetTB: 17-step GFlowNet trajectory-balance forward.
// R10 = R8 structure + 4 blocks/CU with register demand engineered <= 128:
//  - c-coefs in LDS bf16, loaded per chunk INSIDE phase A (transient 16 regs;
//    R9 kept them whole-kernel live -> spill at the 128 budget).
//  - Phase C: 8 sequential 1-acc passes (peak acc 16 regs, was 32). whf L2
//    traffic doubles (R7 proved that's not the bottleneck).
//  - LDS 40896 <= 40960 (=160K/4): bf16 tables, kc packed into amask ushort,
//    logpf in register. bf16 roundings all << 8e7 threshold.

#define NEG_INF (-1000000000.0f)
#define LOG2E 1.4426950408889634f
#define LN2   0.6931471805599453f

// amask ushort: [9:0] action (1023 = dead), [10] new, [15:11] kcnt (full = bit15)
#define A_NEW  0x400

typedef short bf16x8 __attribute__((ext_vector_type(8)));
typedef float f32x16 __attribute__((ext_vector_type(16)));

__device__ __forceinline__ unsigned short f2bf(float x){
  unsigned int u = __float_as_uint(x);
  u = (u + 0x7FFFu + ((u >> 16) & 1u)) >> 16;   // RNE
  return (unsigned short)u;
}
__device__ __forceinline__ float bf2f(unsigned short h){
  return __uint_as_float(((unsigned int)h) << 16);
}
__device__ __forceinline__ unsigned int cvt_pk_bf16(float lo, float hi){
  unsigned int r;
  asm("v_cvt_pk_bf16_f32 %0, %1, %2" : "=v"(r) : "v"(lo), "v"(hi));
  return r;
}
__device__ __forceinline__ float4 ld4bf(const unsigned short* p){
  ushort4 u = *(const ushort4*)p;
  return make_float4(bf2f(u.x), bf2f(u.y), bf2f(u.z), bf2f(u.w));
}

// ---------------------------------------------------------------------------
// Prep: W2 (256x256 f32), Wh (256x513 f32) -> bf16 MFMA fragments.
// Fragment: lane l of tile (kt,ntg) holds M[kt*16+(l>>5)*8+i][ntg*32+(l&31)].
// whf is PRE-SCALED by log2(e) so phase C can use v_exp2 directly.
// ---------------------------------------------------------------------------
__global__ void prep_kernel(const float* __restrict__ W2, const float* __restrict__ Wh,
                            unsigned short* __restrict__ w2f, unsigned short* __restrict__ whf,
                            float* __restrict__ whstop){
  int id = blockIdx.x * 256 + threadIdx.x;
  if (id < 8192){                       // W2 fragments
    int lane = id & 63; int tile = id >> 6;   // tile = kt*8 + ntg
    int ntg = tile & 7, kt = tile >> 3;
    int col = ntg * 32 + (lane & 31);
    int k0  = kt * 16 + (lane >> 5) * 8;
    unsigned int u[4];
#pragma unroll
    for (int p = 0; p < 4; ++p){
      unsigned short lo = f2bf(W2[(k0 + 2*p    ) * 256 + col]);
      unsigned short hi = f2bf(W2[(k0 + 2*p + 1) * 256 + col]);
      u[p] = (unsigned int)lo | ((unsigned int)hi << 16);
    }
    *(uint4*)(w2f + (size_t)id * 8) = make_uint4(u[0], u[1], u[2], u[3]);
  } else if (id < 24576){               // Wh fragments (asset cols 0..511), x log2e
    int id2 = id - 8192;
    int lane = id2 & 63; int tile = id2 >> 6; // tile = kt*16 + ntg
    int ntg = tile & 15, kt = tile >> 4;
    int col = ntg * 32 + (lane & 31);
    int k0  = kt * 16 + (lane >> 5) * 8;
    unsigned int u[4];
#pragma unroll
    for (int p = 0; p < 4; ++p){
      unsigned short lo = f2bf(Wh[(k0 + 2*p    ) * 513 + col] * LOG2E);
      unsigned short hi = f2bf(Wh[(k0 + 2*p + 1) * 513 + col] * LOG2E);
      u[p] = (unsigned int)lo | ((unsigned int)hi << 16);
    }
    *(uint4*)(whf + (size_t)id2 * 8) = make_uint4(u[0], u[1], u[2], u[3]);
  } else if (id < 24832){               // stop column, f32, unscaled
    int k = id - 24576;
    whstop[k] = Wh[k * 513 + 512];
  }
}

// ---------------------------------------------------------------------------
// Fused kernel: 256 threads (4 waves) own 32 samples, 9 chunks x 2 steps.
// Single h tile [64 rows][256 feats] bf16 (h1 then h2 per 32-row pass);
// rows 0-31 = step t, 32-63 = t+1. Byte-XOR swizzle ((row&15)<<4).
// ---------------------------------------------------------------------------
__launch_bounds__(256, 4)
__global__ void gfn_kernel(const int* __restrict__ actions, const float* __restrict__ rp,
                           const float* __restrict__ W1, const float* __restrict__ b1,
                           const float* __restrict__ b2, const float* __restrict__ bh,
                           const unsigned short* __restrict__ w2f,
                           const unsigned short* __restrict__ whf,
                           const float* __restrict__ whstop,
                           float* __restrict__ out)
{
  __shared__ alignas(16) unsigned short h[64 * 256];    // 32768 (h1, then h2)
  __shared__ alignas(16) unsigned short c16[1024];      // 2048: ck/ct/cr/cb bf16
  __shared__ alignas(16) unsigned int selp[16][32];     // 2048 permuted sel bits
  __shared__ alignas(16) unsigned short ebh16[512];     // 1024 exp(bh) bf16
  __shared__ alignas(16) unsigned short b2s16[256];     // 512
  __shared__ alignas(16) unsigned short whst_h[256];    // 512 stop col bf16
  __shared__ alignas(8)  unsigned short amask[18][32];  // 1152
  __shared__ unsigned short pred16[64][4];              // 512
  __shared__ unsigned short stopl16[64];                // 128
  __shared__ unsigned short chosen16[64];               // 128
  __shared__ unsigned short rp16[32];                   // 64   => 40896 total

  const int tid  = threadIdx.x;
  const int wave = tid >> 6;            // 0..3
  const int lane = tid & 63;
  const int ln5  = lane & 31;
  const int lg2  = lane >> 5;
  const int base = blockIdx.x * 32;

  // ---- init ----
  for (int i = tid; i < 1024; i += 256){
    int rrow = i >> 8, f = i & 255;
    float v = (rrow < 3) ? W1[(512 + rrow) * 256 + f] : b1[f];
    c16[i] = f2bf(v);
  }
  b2s16[tid] = f2bf(b2[tid]);
  whst_h[tid] = f2bf(whstop[tid]);
  for (int i = tid; i < 512; i += 256) ebh16[i] = f2bf(__expf(bh[i]));
  const float stopbias = bh[512];
  for (int i = tid; i < 512; i += 256) ((unsigned int*)selp)[i] = 0u;
  int* acts = (int*)h;                  // stage actions in h scratch
  for (int i = tid; i < 544; i += 256) acts[i] = actions[base * 17 + i];
  if (tid < 32) rp16[tid] = f2bf(rp[base + tid]);
  float logpf = 0.f;                    // valid for tid<32 (sample tid)
  __syncthreads();

  // ---- state precompute: O(17^2) scan per sample; no GEMM dependency ----
  if (tid < 32){
    int s = tid, k = 0;
    for (int t = 0; t < 17; ++t){
      int a = acts[s * 17 + t];
      bool alive = (a >= 0);
      bool isnew = alive && (a < 512);
      if (isnew){
        for (int u = 0; u < t; ++u) if (acts[s * 17 + u] == a){ isnew = false; break; }
      }
      int av = alive ? a : 1023;
      amask[t][s] = (unsigned short)(av | (isnew ? A_NEW : 0) | (k << 11));
      if (isnew) ++k;
    }
    amask[17][s] = (unsigned short)(1023 | (k << 11));   // dummy step
  }
  // packed layer-1 running sum: Spk[2*s8+{0,1}] = bf16x2 of feats {0,1},{2,3}
  unsigned int Spk[16];
#pragma unroll
  for (int j = 0; j < 16; ++j) Spk[j] = 0u;
  __syncthreads();

  char* hb = (char*)h;

#pragma unroll 1
  for (int c = 0; c < 9; ++c){
    const int t = c * 2;

    // ---- Phase A: h1 rows for steps t and t+1; thread=(4 feats, 8 samples) ----
    {
      // coefs from LDS each chunk: transient registers (die before B/C)
      const float4 ck4 = ld4bf(&c16[lane * 4]);
      const float4 ct4 = ld4bf(&c16[256 + lane * 4]);
      const float4 cr4 = ld4bf(&c16[512 + lane * 4]);
      const float4 cb4 = ld4bf(&c16[768 + lane * 4]);
      float tf = (float)t;
      float c00 = cb4.x + tf * ct4.x, c01 = cb4.y + tf * ct4.y;
      float c02 = cb4.z + tf * ct4.z, c03 = cb4.w + tf * ct4.w;
      float c10 = c00 + ct4.x, c11 = c01 + ct4.y, c12 = c02 + ct4.z, c13 = c03 + ct4.w;
#pragma unroll
      for (int s8 = 0; s8 < 8; ++s8){
        int s = wave * 8 + s8;
        float rv = bf2f(rp16[s]);
        int m0 = amask[t][s];
        int m1 = amask[t + 1][s];
        unsigned int pk0 = Spk[s8 * 2], pk1 = Spk[s8 * 2 + 1];
        float S0 = __uint_as_float(pk0 << 16);
        float S1 = __uint_as_float(pk0 & 0xFFFF0000u);
        float S2 = __uint_as_float(pk1 << 16);
        float S3 = __uint_as_float(pk1 & 0xFFFF0000u);
        float kf = (float)(m0 >> 11);
        {
          float v0 = fmaxf(S0 + kf * ck4.x + rv * cr4.x + c00, 0.f);
          float v1 = fmaxf(S1 + kf * ck4.y + rv * cr4.y + c01, 0.f);
          float v2 = fmaxf(S2 + kf * ck4.z + rv * cr4.z + c02, 0.f);
          float v3 = fmaxf(S3 + kf * ck4.w + rv * cr4.w + c03, 0.f);
          int byte = (s * 512 + lane * 8) ^ ((s & 15) << 4);
          *(uint2*)(hb + byte) = make_uint2(cvt_pk_bf16(v0, v1), cvt_pk_bf16(v2, v3));
        }
        if (m0 & A_NEW){
          int a = m0 & 1023;
          float4 w = *(const float4*)(W1 + (size_t)a * 256 + lane * 4);
          S0 += w.x; S1 += w.y; S2 += w.z; S3 += w.w;
        }
        float kf1 = (float)(m1 >> 11);
        {
          float v0 = fmaxf(S0 + kf1 * ck4.x + rv * cr4.x + c10, 0.f);
          float v1 = fmaxf(S1 + kf1 * ck4.y + rv * cr4.y + c11, 0.f);
          float v2 = fmaxf(S2 + kf1 * ck4.z + rv * cr4.z + c12, 0.f);
          float v3 = fmaxf(S3 + kf1 * ck4.w + rv * cr4.w + c13, 0.f);
          int byte = ((32 + s) * 512 + lane * 8) ^ ((s & 15) << 4);
          *(uint2*)(hb + byte) = make_uint2(cvt_pk_bf16(v0, v1), cvt_pk_bf16(v2, v3));
        }
        if (m1 & A_NEW){
          int a = m1 & 1023;
          float4 w = *(const float4*)(W1 + (size_t)a * 256 + lane * 4);
          S0 += w.x; S1 += w.y; S2 += w.z; S3 += w.w;
        }
        if ((m0 | m1) & A_NEW){
          Spk[s8 * 2]     = cvt_pk_bf16(S0, S1);
          Spk[s8 * 2 + 1] = cvt_pk_bf16(S2, S3);
        }
      }
    }
    __syncthreads();

    // ---- Phase B (swapped): D'[feat][row]; 2 sequential passes over the
    //      SINGLE h buffer: read h1 rows [32q,+32), barrier, overwrite with h2.
#pragma unroll 1
    for (int q = 0; q < 2; ++q){
      f32x16 aB0, aB1;
#pragma unroll
      for (int i = 0; i < 16; ++i){ aB0[i] = 0.f; aB1[i] = 0.f; }
#pragma unroll 4
      for (int kt = 0; kt < 16; ++kt){
        int off = kt * 32 + lg2 * 16;
        int rr = q * 32 + ln5;
        bf16x8 sf = *(const bf16x8*)(hb + ((rr * 512 + off) ^ ((ln5 & 15) << 4)));
        bf16x8 w0 = *(const bf16x8*)(w2f + ((size_t)((kt * 8 + wave * 2    ) * 64 + lane)) * 8);
        bf16x8 w1 = *(const bf16x8*)(w2f + ((size_t)((kt * 8 + wave * 2 + 1) * 64 + lane)) * 8);
        aB0 = __builtin_amdgcn_mfma_f32_32x32x16_bf16(w0, sf, aB0, 0, 0, 0);
        aB1 = __builtin_amdgcn_mfma_f32_32x32x16_bf16(w1, sf, aB1, 0, 0, 0);
      }
      __syncthreads();   // all waves done reading h1 rows [32q,+32)
      int rr = q * 32 + ln5;
#pragma unroll
      for (int g = 0; g < 4; ++g){
        int f0 = wave * 64 + g * 8 + lg2 * 4;
        int f1 = f0 + 32;
        float4 bb0 = ld4bf(&b2s16[f0]);
        float4 bb1 = ld4bf(&b2s16[f1]);
        {
          float v0 = fmaxf(aB0[g*4+0] + bb0.x, 0.f), v1 = fmaxf(aB0[g*4+1] + bb0.y, 0.f);
          float v2 = fmaxf(aB0[g*4+2] + bb0.z, 0.f), v3 = fmaxf(aB0[g*4+3] + bb0.w, 0.f);
          int byte = (rr * 512 + f0 * 2) ^ ((ln5 & 15) << 4);
          *(uint2*)(hb + byte) = make_uint2(cvt_pk_bf16(v0, v1), cvt_pk_bf16(v2, v3));
        }
        {
          float v0 = fmaxf(aB1[g*4+0] + bb1.x, 0.f), v1 = fmaxf(aB1[g*4+1] + bb1.y, 0.f);
          float v2 = fmaxf(aB1[g*4+2] + bb1.z, 0.f), v3 = fmaxf(aB1[g*4+3] + bb1.w, 0.f);
          int byte = (rr * 512 + f1 * 2) ^ ((ln5 & 15) << 4);
          *(uint2*)(hb + byte) = make_uint2(cvt_pk_bf16(v0, v1), cvt_pk_bf16(v2, v3));
        }
      }
    }
    __syncthreads();   // h2 fully written

    // ---- stop logit (col 512): 4 threads/row, 64 rows ----
    {
      int row = tid >> 2, f4 = tid & 3;
      float sp = 0.f;
#pragma unroll
      for (int c8 = 0; c8 < 8; ++c8){
        int sl = c8 * 4 + f4;
        int byte = (row * 512 + sl * 16) ^ ((row & 15) << 4);
        uint4 q = *(const uint4*)(hb + byte);
        unsigned int qq[4] = {q.x, q.y, q.z, q.w};
#pragma unroll
        for (int p = 0; p < 4; ++p){
          int f = sl * 8 + 2 * p;
          sp += bf2f((unsigned short)(qq[p] & 0xFFFFu)) * bf2f(whst_h[f])
              + bf2f((unsigned short)(qq[p] >> 16))     * bf2f(whst_h[f + 1]);
        }
      }
      sp += __shfl_xor(sp, 1);
      sp += __shfl_xor(sp, 2);
      if (f4 == 0){
        int kcv = amask[t + (row >> 5)][row & 31] >> 11;
        stopl16[row] = f2bf((kcv == 0) ? NEG_INF : sp + stopbias);
      }
    }

    // ---- Phase C (swapped): lane owns sample ln5 (both steps); 8 sequential
    //      1-acc passes (pt = wave*4 + (p>>1), row-tile rt = p&1).
    {
      int mt  = amask[t][ln5];
      int mt1 = amask[t + 1][ln5];
      int av0 = mt & 1023, av1 = mt1 & 1023;
      int pa = (mt & A_NEW) ? av0 : -1;     // patch col for step t+1 mask
      float sum0 = 0.f, sum1 = 0.f;
#pragma unroll 1
      for (int p = 0; p < 8; ++p){
        int pt = wave * 4 + (p >> 1);
        int rt = p & 1;
        f32x16 a0;
#pragma unroll
        for (int i = 0; i < 16; ++i) a0[i] = 0.f;
#pragma unroll 4
        for (int kt = 0; kt < 16; ++kt){
          int off = kt * 32 + lg2 * 16;
          int row = rt * 32 + ln5;
          bf16x8 b0 = *(const bf16x8*)(hb + ((row * 512 + off) ^ ((ln5 & 15) << 4)));
          bf16x8 w = *(const bf16x8*)(whf + ((size_t)((kt * 16 + pt) * 64 + lane)) * 8);
          a0 = __builtin_amdgcn_mfma_f32_32x32x16_bf16(w, b0, a0, 0, 0, 0);
        }
        // 16-bit mask in fragment order (bit r)
        unsigned wsel = (selp[pt][ln5] >> (lg2 * 16)) & 0xFFFFu;
        unsigned msk; int av;
        if (rt == 0){
          msk = (mt & 0x8000) ? 0xFFFFu : wsel;
          av = av0;
        } else {
          msk = (mt1 & 0x8000) ? 0xFFFFu : wsel;
          if (pa >= 0 && (pa >> 5) == pt && (((pa >> 2) & 1) == lg2))
            msk |= 1u << ((pa & 3) | (((pa >> 3) & 3) << 2));
          av = av1;
        }
        int tr = (av < 512 && (av >> 5) == pt && (((av >> 2) & 1) == lg2))
                 ? ((av & 3) | (((av >> 3) & 3) << 2)) : -1;
        float sacc = 0.f, cv = 0.f, ce = 1.f;
#pragma unroll
        for (int g = 0; g < 4; ++g){
          const ushort4 ebu = *(const ushort4*)&ebh16[pt * 32 + g * 8 + lg2 * 4];
          float ee[4] = { bf2f(ebu.x), bf2f(ebu.y), bf2f(ebu.z), bf2f(ebu.w) };
#pragma unroll
          for (int j = 0; j < 4; ++j){
            int r = g * 4 + j;
            float v = ((msk >> r) & 1u) ? NEG_INF : a0[r];
            sacc = fmaf(__builtin_amdgcn_exp2f(v), ee[j], sacc);
            if (r == tr){ cv = v; ce = ee[j]; }
          }
        }
        if (tr >= 0){
          float ch = (cv == NEG_INF) ? NEG_INF : fmaf(cv, LN2, __logf(ce));
          chosen16[rt * 32 + ln5] = f2bf(ch);
        }
        if (rt == 0) sum0 += sacc; else sum1 += sacc;
      }
      sum0 += __shfl_xor(sum0, 32);
      sum1 += __shfl_xor(sum1, 32);
      if (lg2 == 0){
        pred16[ln5][wave]      = f2bf(sum0);
        pred16[32 + ln5][wave] = f2bf(sum1);
      }
    }
    __syncthreads();

    // ---- finalize both steps: lse, logpf (register), selp commit ----
    if (tid < 32){
      int s = tid;
      int m0 = amask[t][s];
      int m1 = amask[t + 1][s];
      int av0 = m0 & 1023, av1 = m1 & 1023;
      {
        float tot = __expf(bf2f(stopl16[s]))
                  + bf2f(pred16[s][0]) + bf2f(pred16[s][1])
                  + bf2f(pred16[s][2]) + bf2f(pred16[s][3]);
        float lse = __logf(tot);
        if (av0 != 1023)
          logpf += ((av0 == 512) ? bf2f(stopl16[s]) : bf2f(chosen16[s])) - lse;
        if (m0 & A_NEW){
          int pt = av0 >> 5, rf = av0 & 31;
          selp[pt][s] |= 1u << ((((rf >> 2) & 1) << 4) | (rf & 3) | (((rf >> 3) & 3) << 2));
        }
      }
      {
        int row = 32 + s;
        float tot = __expf(bf2f(stopl16[row]))
                  + bf2f(pred16[row][0]) + bf2f(pred16[row][1])
                  + bf2f(pred16[row][2]) + bf2f(pred16[row][3]);
        float lse = __logf(tot);
        if (av1 != 1023)
          logpf += ((av1 == 512) ? bf2f(stopl16[row]) : bf2f(chosen16[row])) - lse;
        if (m1 & A_NEW){
          int pt = av1 >> 5, rf = av1 & 31;
          selp[pt][s] |= 1u << ((((rf >> 2) & 1) << 4) | (rf & 3) | (((rf >> 3) & 3) << 2));
        }
      }
    }
    __syncthreads();
  } // chunk loop

  if (tid < 32) out[base + tid] = logpf;
}

extern "C" void kernel_launch(void* const* d_in, const int* in_sizes, int n_in,
                              void* d_out, int out_size, void* d_ws, size_t ws_size,
                              hipStream_t stream)
{
  const int*   actions = (const int*)d_in[0];
  const float* rp  = (const float*)d_in[1];
  const float* W1  = (const float*)d_in[2];
  const float* b1  = (const float*)d_in[3];
  const float* W2  = (const float*)d_in[4];
  const float* b2  = (const float*)d_in[5];
  const float* Wh  = (const float*)d_in[6];
  const float* bh  = (const float*)d_in[7];
  float* out = (float*)d_out;

  unsigned short* w2f = (unsigned short*)d_ws;          // 65536  bf16 (128 KB)
  unsigned short* whf = w2f + 65536;                    // 131072 bf16 (256 KB)
  float* whstop = (float*)(whf + 131072);               // 256 f32

  prep_kernel<<<97, 256, 0, stream>>>(W2, Wh, w2f, whf, whstop);
  gfn_kernel<<<2048, 256, 0, stream>>>(actions, rp, W1, b1, b2, bh, w2f, whf, whstop, out);
}